// Round 8
// baseline (658.314 us; speedup 1.0000x reference)
//
#include <hip/hip_runtime.h>
#include <hip/hip_bf16.h>

// B=64, N=2048, C=256, H=8, Ch=32, M = B*N = 131072, qkv dim = 768
// Fused: x -> qkv -> head-attention -> proj -> out, one kernel, 16 tokens/block.

typedef __attribute__((ext_vector_type(8))) short bf16x8;
typedef __attribute__((ext_vector_type(4))) short bf16x4;
typedef __attribute__((ext_vector_type(4))) float f32x4;

__device__ __forceinline__ short f2bf(float f) {
    unsigned u = __builtin_bit_cast(unsigned, f);
    unsigned r = (u + 0x7FFFu + ((u >> 16) & 1u)) >> 16;  // RNE
    return (short)r;
}
__device__ __forceinline__ float bf2f(short h) {
    unsigned u = ((unsigned)(unsigned short)h) << 16;
    return __builtin_bit_cast(float, u);
}

// ---------------- K0: convert weights fp32 -> bf16 ----------------
__global__ void k0_convert(const float* __restrict__ qkv_w,
                           const float* __restrict__ proj_w,
                           short* __restrict__ wq_bf,
                           short* __restrict__ wp_bf) {
    int i = blockIdx.x * 256 + threadIdx.x;   // 262144 total
    if (i < 196608) {
        wq_bf[i] = f2bf(qkv_w[i]);
    } else {
        wp_bf[i - 196608] = f2bf(proj_w[i - 196608]);
    }
}

// ---------------- K1: fully fused ----------------
// 512 threads (8 waves), 16 tokens per block, 8192 blocks.
// LDS plan (24832 B total, sequential overlays with barriers):
//   phase A: x tile   [16][512B]  bf16, XOR swizzle            @ [0, 8K)
//   phase Y: qkv out  [16][1552B] bf16 (stride 776 shorts)     @ [0, 24832)
//   phase O: attn out [16][512B]  bf16, XOR swizzle (proj in)  @ [0, 8K)
__global__ __launch_bounds__(512, 6) void k1_fused(
    const float* __restrict__ x,      // [131072][256] fp32
    const short* __restrict__ wq,     // [768][256] bf16 bits
    const float* __restrict__ qkv_b,  // [768] fp32
    const short* __restrict__ wp,     // [256][256] bf16 bits
    const float* __restrict__ proj_b, // [256] fp32
    float* __restrict__ out)          // [131072][256] fp32
{
    __shared__ __align__(16) char smem[24832];
    const int tid  = threadIdx.x;
    const int lane = tid & 63;
    const int wave = tid >> 6;
    const int t0   = blockIdx.x * 16;          // first token (16-aligned)

    const int fr = lane & 15, fq = lane >> 4;  // frag row, k-quarter

    // ---- stage x[t0..t0+16][0..256] fp32 -> bf16 LDS, XOR swizzle ----
    {
        const int r = tid >> 5, s = tid & 31;  // row 0..15, 16B-chunk 0..31
        const float4* src = (const float4*)(x + (long)(t0 + r) * 256 + s * 8);
        float4 f0 = src[0], f1 = src[1];
        bf16x8 v;
        v[0] = f2bf(f0.x); v[1] = f2bf(f0.y); v[2] = f2bf(f0.z); v[3] = f2bf(f0.w);
        v[4] = f2bf(f1.x); v[5] = f2bf(f1.y); v[6] = f2bf(f1.z); v[7] = f2bf(f1.w);
        *(bf16x8*)(smem + r * 512 + ((s * 16) ^ ((r & 7) << 4))) = v;
    }
    __syncthreads();

    // ---- QKV MFMA: wave w -> qkv cols [96w, 96w+96), 16 token-rows ----
    f32x4 acc[6];
#pragma unroll
    for (int j = 0; j < 6; ++j) acc[j] = (f32x4){0.f, 0.f, 0.f, 0.f};
    {
        const int nbq = wave * 96;
        const short* wq_base = wq + (nbq + fr) * 256 + fq * 8;
#pragma unroll
        for (int ks = 0; ks < 8; ++ks) {
            const int kbyte = ks * 64 + fq * 16;
            bf16x8 bX = *(const bf16x8*)(smem + fr * 512 + (kbyte ^ ((fr & 7) << 4)));
            // two half-batches of weight frags to cap register pressure
            bf16x8 aW0 = *(const bf16x8*)(wq_base + 0 * 4096 + ks * 32);
            bf16x8 aW1 = *(const bf16x8*)(wq_base + 1 * 4096 + ks * 32);
            bf16x8 aW2 = *(const bf16x8*)(wq_base + 2 * 4096 + ks * 32);
            acc[0] = __builtin_amdgcn_mfma_f32_16x16x32_bf16(aW0, bX, acc[0], 0, 0, 0);
            acc[1] = __builtin_amdgcn_mfma_f32_16x16x32_bf16(aW1, bX, acc[1], 0, 0, 0);
            acc[2] = __builtin_amdgcn_mfma_f32_16x16x32_bf16(aW2, bX, acc[2], 0, 0, 0);
            bf16x8 aW3 = *(const bf16x8*)(wq_base + 3 * 4096 + ks * 32);
            bf16x8 aW4 = *(const bf16x8*)(wq_base + 4 * 4096 + ks * 32);
            bf16x8 aW5 = *(const bf16x8*)(wq_base + 5 * 4096 + ks * 32);
            acc[3] = __builtin_amdgcn_mfma_f32_16x16x32_bf16(aW3, bX, acc[3], 0, 0, 0);
            acc[4] = __builtin_amdgcn_mfma_f32_16x16x32_bf16(aW4, bX, acc[4], 0, 0, 0);
            acc[5] = __builtin_amdgcn_mfma_f32_16x16x32_bf16(aW5, bX, acc[5], 0, 0, 0);
        }
    }
    __syncthreads();   // x tile dead; LDS becomes Y

    // ---- Y epilogue: bias + bf16, Y[tok = fr][768], stride 776 shorts ----
    {
        const int nbq = wave * 96;
#pragma unroll
        for (int j = 0; j < 6; ++j) {
            const int n0 = nbq + j * 16 + fq * 4;
            float4 bias = *(const float4*)(qkv_b + n0);
            bf16x4 y;
            y[0] = f2bf(acc[j][0] + bias.x);
            y[1] = f2bf(acc[j][1] + bias.y);
            y[2] = f2bf(acc[j][2] + bias.z);
            y[3] = f2bf(acc[j][3] + bias.w);
            *(bf16x4*)(smem + fr * 1552 + n0 * 2) = y;
        }
    }
    __syncthreads();

    // ---- attention: 32 threads/token = 8 heads x 4 ch-quarters ----
    float o[8];
    int orow, ocol;
    {
        const int t = tid >> 5, sub = tid & 31;
        const int h = sub & 7, qt = sub >> 3;      // head, ch-quarter (8 ch each)
        const char* Yrow = smem + t * 1552;
        const float scale = 0.17677669529663687f; // 1/sqrt(32)

        float q[8];
        {
            bf16x8 qv = *(const bf16x8*)(Yrow + h * 64 + qt * 16);
#pragma unroll
            for (int c = 0; c < 8; ++c) q[c] = bf2f(qv[c]);
        }
        float s[8];
#pragma unroll
        for (int g = 0; g < 8; ++g) {
            bf16x8 kv = *(const bf16x8*)(Yrow + 512 + g * 64 + qt * 16);
            float p = 0.f;
#pragma unroll
            for (int c = 0; c < 8; ++c) p += q[c] * bf2f(kv[c]);
            p += __shfl_xor(p, 8);    // combine qt bit0 (same token, same head)
            p += __shfl_xor(p, 16);   // combine qt bit1
            s[g] = p * scale;
        }
        float mx = s[0];
#pragma unroll
        for (int g = 1; g < 8; ++g) mx = fmaxf(mx, s[g]);
        float pw[8], psum = 0.f;
#pragma unroll
        for (int g = 0; g < 8; ++g) { pw[g] = __expf(s[g] - mx); psum += pw[g]; }
        const float inv = 1.f / psum;

#pragma unroll
        for (int c = 0; c < 8; ++c) o[c] = 0.f;
#pragma unroll
        for (int g = 0; g < 8; ++g) {
            bf16x8 vv = *(const bf16x8*)(Yrow + 1024 + g * 64 + qt * 16);
#pragma unroll
            for (int c = 0; c < 8; ++c) o[c] += pw[g] * bf2f(vv[c]);
        }
#pragma unroll
        for (int c = 0; c < 8; ++c) o[c] *= inv;

        // proj-input row/col for this 16B chunk:
        // row' = h*2 + (t>>3) (in-tile), col bytes = (t&7)*64 + qt*16
        orow = h * 2 + (t >> 3);
        ocol = (t & 7) * 64 + qt * 16;
    }
    __syncthreads();   // all Y reads complete before O overlays Y[0,8K)

    // ---- write O tile [16][512B], XOR swizzle (same scheme as x tile) ----
    {
        bf16x8 ov;
#pragma unroll
        for (int c = 0; c < 8; ++c) ov[c] = f2bf(o[c]);
        *(bf16x8*)(smem + orow * 512 + (ocol ^ ((orow & 7) << 4))) = ov;
    }
    __syncthreads();

    // ---- proj MFMA: wave w -> out cols [32w, 32w+32), 16 rows from O ----
    {
        const int nbp = wave * 32;
        const short* wp_base = wp + (nbp + fr) * 256 + fq * 8;
        f32x4 pacc0 = (f32x4){0.f, 0.f, 0.f, 0.f};
        f32x4 pacc1 = (f32x4){0.f, 0.f, 0.f, 0.f};
#pragma unroll
        for (int ks = 0; ks < 8; ++ks) {
            bf16x8 bO = *(const bf16x8*)(smem + fr * 512 + ((ks * 64 + fq * 16) ^ ((fr & 7) << 4)));
            bf16x8 w0 = *(const bf16x8*)(wp_base + ks * 32);           // rows nbp+fr
            bf16x8 w1 = *(const bf16x8*)(wp_base + 4096 + ks * 32);    // rows nbp+16+fr
            pacc0 = __builtin_amdgcn_mfma_f32_16x16x32_bf16(w0, bO, pacc0, 0, 0, 0);
            pacc1 = __builtin_amdgcn_mfma_f32_16x16x32_bf16(w1, bO, pacc1, 0, 0, 0);
        }

        // epilogue: O-tile row fr -> out row r' = b*2048 + h*256 + (n>>3) + oct
        const int  h   = fr >> 1, oct = fr & 1;
        const long b   = (long)(t0 >> 11);
        const int  n   = t0 & 2047;
        const long rp  = b * 2048 + h * 256 + (n >> 3) + oct;
        {
            const int n0 = nbp + fq * 4;
            float4 bias = *(const float4*)(proj_b + n0);
            float4 res = {pacc0[0] + bias.x, pacc0[1] + bias.y,
                          pacc0[2] + bias.z, pacc0[3] + bias.w};
            *(float4*)(out + rp * 256 + n0) = res;
        }
        {
            const int n0 = nbp + 16 + fq * 4;
            float4 bias = *(const float4*)(proj_b + n0);
            float4 res = {pacc1[0] + bias.x, pacc1[1] + bias.y,
                          pacc1[2] + bias.z, pacc1[3] + bias.w};
            *(float4*)(out + rp * 256 + n0) = res;
        }
    }
}

extern "C" void kernel_launch(void* const* d_in, const int* in_sizes, int n_in,
                              void* d_out, int out_size, void* d_ws, size_t ws_size,
                              hipStream_t stream) {
    const float* x      = (const float*)d_in[0];
    const float* qkv_w  = (const float*)d_in[1];
    const float* qkv_b  = (const float*)d_in[2];
    const float* proj_w = (const float*)d_in[3];
    const float* proj_b = (const float*)d_in[4];
    float* out = (float*)d_out;

    char* ws = (char*)d_ws;
    short* wq_bf = (short*)ws;                     // 393,216 B
    short* wp_bf = (short*)(ws + 393216);          // 131,072 B

    k0_convert<<<1024, 256, 0, stream>>>(qkv_w, proj_w, wq_bf, wp_bf);
    k1_fused<<<8192, 512, 0, stream>>>(x, wq_bf, qkv_b, wp_bf, proj_b, out);
}

// Round 9
// 566.664 us; speedup vs baseline: 1.1617x; 1.1617x over previous
//
#include <hip/hip_runtime.h>
#include <hip/hip_bf16.h>

// B=64, N=2048, C=256, H=8, Ch=32, M=131072, qkv dim=768
// Pipeline: k0 (weights->bf16), k1 QKV GEMM (x fp32 in-flight convert),
//           k2 attention (Y->out2 shuffled), k3 proj GEMM (out2->out fp32).
// Fallback to the r8 fused kernel if ws_size can't hold Y (201MB).

typedef __attribute__((ext_vector_type(8))) short bf16x8;
typedef __attribute__((ext_vector_type(4))) short bf16x4;
typedef __attribute__((ext_vector_type(4))) float f32x4;

__device__ __forceinline__ short f2bf(float f) {
    unsigned u = __builtin_bit_cast(unsigned, f);
    unsigned r = (u + 0x7FFFu + ((u >> 16) & 1u)) >> 16;  // RNE
    return (short)r;
}
__device__ __forceinline__ float bf2f(short h) {
    unsigned u = ((unsigned)(unsigned short)h) << 16;
    return __builtin_bit_cast(float, u);
}

// ---------------- K0: convert weights fp32 -> bf16 ----------------
__global__ void k0_convert(const float* __restrict__ qkv_w,
                           const float* __restrict__ proj_w,
                           short* __restrict__ wq_bf,
                           short* __restrict__ wp_bf) {
    int i = blockIdx.x * 256 + threadIdx.x;   // 262144 total
    if (i < 196608) {
        wq_bf[i] = f2bf(qkv_w[i]);
    } else {
        wp_bf[i - 196608] = f2bf(proj_w[i - 196608]);
    }
}

// ---------------- K1: QKV GEMM  Y[M][768] = x @ wq^T + b ----------------
// 256 thr (4 waves, 2x2), tile 128x128, BK=32, 8 K-steps, grid 1536 (6N x 256Mg),
// each block strides 4 M-tiles. A staged from fp32 x with in-flight convert.
// LDS XOR swizzle: logical (row, u16B) at short-index row*32 + ((u^(row&3))*8).
__global__ __launch_bounds__(256, 3) void k1_qkv(
    const float* __restrict__ x,      // [131072][256] fp32
    const short* __restrict__ wq,     // [768][256] bf16
    const float* __restrict__ qkv_b,  // [768] fp32
    short* __restrict__ Y)            // [131072][768] bf16
{
    __shared__ short As[128 * 32];
    __shared__ short Bs[128 * 32];
    const int tid = threadIdx.x, lane = tid & 63, wave = tid >> 6;
    const int wr = wave >> 1, wc = wave & 1;
    const int fr = lane & 15, fq = lane >> 4;
    const int nt = blockIdx.x % 6;
    const int mg = blockIdx.x / 6;            // 0..255
    const int n0 = nt * 128;
    const int srow = tid >> 1, shalf = tid & 1;
    const int ssw0 = ((shalf * 2 + 0) ^ (srow & 3)) * 8;   // staging swizzled short-offsets
    const int ssw1 = ((shalf * 2 + 1) ^ (srow & 3)) * 8;
    const int fsw = (fq ^ (fr & 3)) * 8;                    // frag-read swizzled short-offset

    for (int g = 0; g < 4; ++g) {
        const long m0 = (long)(mg + g * 256) * 128;
        f32x4 acc[4][4];
#pragma unroll
        for (int i = 0; i < 4; ++i)
#pragma unroll
            for (int j = 0; j < 4; ++j) acc[i][j] = (f32x4){0.f, 0.f, 0.f, 0.f};

        float4 sa[2][4];
        bf16x8 sb[2][2];
        // prologue: issue ks=0 loads
        {
            const float4* ap = (const float4*)(x + (m0 + srow) * 256 + shalf * 16);
#pragma unroll
            for (int j = 0; j < 4; ++j) sa[0][j] = ap[j];
            const short* bp = wq + (n0 + srow) * 256 + shalf * 16;
            sb[0][0] = *(const bf16x8*)(bp);
            sb[0][1] = *(const bf16x8*)(bp + 8);
        }
#pragma unroll
        for (int ks = 0; ks < 8; ++ks) {
            const int cur = ks & 1, nxt = cur ^ 1;
            __syncthreads();   // prev-tile frag reads done
            // write staged regs -> LDS (swizzled)
            {
                bf16x8 v0, v1;
                v0[0]=f2bf(sa[cur][0].x); v0[1]=f2bf(sa[cur][0].y); v0[2]=f2bf(sa[cur][0].z); v0[3]=f2bf(sa[cur][0].w);
                v0[4]=f2bf(sa[cur][1].x); v0[5]=f2bf(sa[cur][1].y); v0[6]=f2bf(sa[cur][1].z); v0[7]=f2bf(sa[cur][1].w);
                v1[0]=f2bf(sa[cur][2].x); v1[1]=f2bf(sa[cur][2].y); v1[2]=f2bf(sa[cur][2].z); v1[3]=f2bf(sa[cur][2].w);
                v1[4]=f2bf(sa[cur][3].x); v1[5]=f2bf(sa[cur][3].y); v1[6]=f2bf(sa[cur][3].z); v1[7]=f2bf(sa[cur][3].w);
                *(bf16x8*)(&As[srow * 32 + ssw0]) = v0;
                *(bf16x8*)(&As[srow * 32 + ssw1]) = v1;
                *(bf16x8*)(&Bs[srow * 32 + ssw0]) = sb[cur][0];
                *(bf16x8*)(&Bs[srow * 32 + ssw1]) = sb[cur][1];
            }
            __syncthreads();   // tile visible
            if (ks < 7) {      // early-issue next tile (hides under MFMAs)
                const int k1o = (ks + 1) * 32;
                const float4* ap = (const float4*)(x + (m0 + srow) * 256 + k1o + shalf * 16);
#pragma unroll
                for (int j = 0; j < 4; ++j) sa[nxt][j] = ap[j];
                const short* bp = wq + (n0 + srow) * 256 + k1o + shalf * 16;
                sb[nxt][0] = *(const bf16x8*)(bp);
                sb[nxt][1] = *(const bf16x8*)(bp + 8);
            }
            bf16x8 af[4], bf[4];
#pragma unroll
            for (int nj = 0; nj < 4; ++nj)
                af[nj] = *(const bf16x8*)(&Bs[(wc * 64 + nj * 16 + fr) * 32 + fsw]);
#pragma unroll
            for (int mi = 0; mi < 4; ++mi)
                bf[mi] = *(const bf16x8*)(&As[(wr * 64 + mi * 16 + fr) * 32 + fsw]);
#pragma unroll
            for (int mi = 0; mi < 4; ++mi)
#pragma unroll
                for (int nj = 0; nj < 4; ++nj)
                    acc[mi][nj] = __builtin_amdgcn_mfma_f32_16x16x32_bf16(af[nj], bf[mi], acc[mi][nj], 0, 0, 0);
        }
        // epilogue: bias + bf16 store
#pragma unroll
        for (int mi = 0; mi < 4; ++mi) {
            const long m = m0 + wr * 64 + mi * 16 + fr;
#pragma unroll
            for (int nj = 0; nj < 4; ++nj) {
                const int nc = n0 + wc * 64 + nj * 16 + fq * 4;
                float4 bb = *(const float4*)(qkv_b + nc);
                bf16x4 y;
                y[0] = f2bf(acc[mi][nj][0] + bb.x);
                y[1] = f2bf(acc[mi][nj][1] + bb.y);
                y[2] = f2bf(acc[mi][nj][2] + bb.z);
                y[3] = f2bf(acc[mi][nj][3] + bb.w);
                *(bf16x4*)(&Y[m * 768 + nc]) = y;
            }
        }
        if (g < 3) __syncthreads();   // LDS reuse across M-tiles
    }
}

// ---------------- K2: attention  Y -> out2 (shuffled) ----------------
// 1024 blocks x 512 thr, 8 grid-stride passes, 32 threads/token (8 heads x 4 qt).
__global__ __launch_bounds__(512, 6) void k2_attn(
    const short* __restrict__ Y,      // [131072][768] bf16
    short* __restrict__ out2)         // [131072][256] bf16, shuffled
{
    const int tid = threadIdx.x;
    const int t_in = tid >> 5, sub = tid & 31;
    const int h = sub & 7, qt = sub >> 3;
    const float scale = 0.17677669529663687f;  // 1/sqrt(32)
#pragma unroll 1
    for (int p = 0; p < 8; ++p) {
        const long tg = ((long)p * 1024 + blockIdx.x) * 16 + t_in;
        const short* Yr = Y + tg * 768;
        float q[8];
        {
            bf16x8 qv = *(const bf16x8*)(Yr + h * 32 + qt * 8);
#pragma unroll
            for (int c = 0; c < 8; ++c) q[c] = bf2f(qv[c]);
        }
        float s[8];
#pragma unroll
        for (int g = 0; g < 8; ++g) {
            bf16x8 kv = *(const bf16x8*)(Yr + 256 + g * 32 + qt * 8);
            float pp = 0.f;
#pragma unroll
            for (int c = 0; c < 8; ++c) pp += q[c] * bf2f(kv[c]);
            pp += __shfl_xor(pp, 8);
            pp += __shfl_xor(pp, 16);
            s[g] = pp * scale;
        }
        float mx = s[0];
#pragma unroll
        for (int g = 1; g < 8; ++g) mx = fmaxf(mx, s[g]);
        float pw[8], psum = 0.f;
#pragma unroll
        for (int g = 0; g < 8; ++g) { pw[g] = __expf(s[g] - mx); psum += pw[g]; }
        const float inv = 1.f / psum;
        float o[8];
#pragma unroll
        for (int c = 0; c < 8; ++c) o[c] = 0.f;
#pragma unroll
        for (int g = 0; g < 8; ++g) {
            bf16x8 vv = *(const bf16x8*)(Yr + 512 + g * 32 + qt * 8);
#pragma unroll
            for (int c = 0; c < 8; ++c) o[c] += pw[g] * bf2f(vv[c]);
        }
        const long b = tg >> 11;
        const int  n = (int)(tg & 2047);
        const int  np = (h * 2048 + n) >> 3;
        const int  cp = (n & 7) * 32 + qt * 8;
        bf16x8 ov;
#pragma unroll
        for (int c = 0; c < 8; ++c) ov[c] = f2bf(o[c] * inv);
        *(bf16x8*)(out2 + (b * 2048 + np) * 256 + cp) = ov;
    }
}

// ---------------- K3: proj GEMM  out[M][256] = out2 @ wp^T + b ----------------
// Same structure as K1; 2048 blocks (2N x 1024M), no striding, fp32 output.
__global__ __launch_bounds__(256, 3) void k3_proj(
    const short* __restrict__ out2,   // [131072][256] bf16
    const short* __restrict__ wp,     // [256][256] bf16
    const float* __restrict__ proj_b, // [256] fp32
    float* __restrict__ out)          // [131072][256] fp32
{
    __shared__ short As[128 * 32];
    __shared__ short Bs[128 * 32];
    const int tid = threadIdx.x, lane = tid & 63, wave = tid >> 6;
    const int wr = wave >> 1, wc = wave & 1;
    const int fr = lane & 15, fq = lane >> 4;
    const int nt = blockIdx.x & 1;
    const long m0 = (long)(blockIdx.x >> 1) * 128;
    const int n0 = nt * 128;
    const int srow = tid >> 1, shalf = tid & 1;
    const int ssw0 = ((shalf * 2 + 0) ^ (srow & 3)) * 8;
    const int ssw1 = ((shalf * 2 + 1) ^ (srow & 3)) * 8;
    const int fsw = (fq ^ (fr & 3)) * 8;

    f32x4 acc[4][4];
#pragma unroll
    for (int i = 0; i < 4; ++i)
#pragma unroll
        for (int j = 0; j < 4; ++j) acc[i][j] = (f32x4){0.f, 0.f, 0.f, 0.f};

    bf16x8 sa[2][2], sb[2][2];
    {
        const short* ap = out2 + (m0 + srow) * 256 + shalf * 16;
        sa[0][0] = *(const bf16x8*)(ap);
        sa[0][1] = *(const bf16x8*)(ap + 8);
        const short* bp = wp + (n0 + srow) * 256 + shalf * 16;
        sb[0][0] = *(const bf16x8*)(bp);
        sb[0][1] = *(const bf16x8*)(bp + 8);
    }
#pragma unroll
    for (int ks = 0; ks < 8; ++ks) {
        const int cur = ks & 1, nxt = cur ^ 1;
        __syncthreads();
        *(bf16x8*)(&As[srow * 32 + ssw0]) = sa[cur][0];
        *(bf16x8*)(&As[srow * 32 + ssw1]) = sa[cur][1];
        *(bf16x8*)(&Bs[srow * 32 + ssw0]) = sb[cur][0];
        *(bf16x8*)(&Bs[srow * 32 + ssw1]) = sb[cur][1];
        __syncthreads();
        if (ks < 7) {
            const int k1o = (ks + 1) * 32;
            const short* ap = out2 + (m0 + srow) * 256 + k1o + shalf * 16;
            sa[nxt][0] = *(const bf16x8*)(ap);
            sa[nxt][1] = *(const bf16x8*)(ap + 8);
            const short* bp = wp + (n0 + srow) * 256 + k1o + shalf * 16;
            sb[nxt][0] = *(const bf16x8*)(bp);
            sb[nxt][1] = *(const bf16x8*)(bp + 8);
        }
        bf16x8 af[4], bfr[4];
#pragma unroll
        for (int nj = 0; nj < 4; ++nj)
            af[nj] = *(const bf16x8*)(&Bs[(wc * 64 + nj * 16 + fr) * 32 + fsw]);
#pragma unroll
        for (int mi = 0; mi < 4; ++mi)
            bfr[mi] = *(const bf16x8*)(&As[(wr * 64 + mi * 16 + fr) * 32 + fsw]);
#pragma unroll
        for (int mi = 0; mi < 4; ++mi)
#pragma unroll
            for (int nj = 0; nj < 4; ++nj)
                acc[mi][nj] = __builtin_amdgcn_mfma_f32_16x16x32_bf16(af[nj], bfr[mi], acc[mi][nj], 0, 0, 0);
    }
#pragma unroll
    for (int mi = 0; mi < 4; ++mi) {
        const long m = m0 + wr * 64 + mi * 16 + fr;
#pragma unroll
        for (int nj = 0; nj < 4; ++nj) {
            const int nc = n0 + wc * 64 + nj * 16 + fq * 4;
            float4 bb = *(const float4*)(proj_b + nc);
            float4 res = {acc[mi][nj][0] + bb.x, acc[mi][nj][1] + bb.y,
                          acc[mi][nj][2] + bb.z, acc[mi][nj][3] + bb.w};
            *(float4*)(out + m * 256 + nc) = res;
        }
    }
}

// ================= r8 fused kernel: fallback if ws too small =================
__global__ __launch_bounds__(512, 6) void k1_fused(
    const float* __restrict__ x, const short* __restrict__ wq,
    const float* __restrict__ qkv_b, const short* __restrict__ wp,
    const float* __restrict__ proj_b, float* __restrict__ out)
{
    __shared__ __align__(16) char smem[24832];
    const int tid = threadIdx.x;
    const int lane = tid & 63;
    const int wave = tid >> 6;
    const int t0 = blockIdx.x * 16;
    const int fr = lane & 15, fq = lane >> 4;
    {
        const int r = tid >> 5, s = tid & 31;
        const float4* src = (const float4*)(x + (long)(t0 + r) * 256 + s * 8);
        float4 f0 = src[0], f1 = src[1];
        bf16x8 v;
        v[0] = f2bf(f0.x); v[1] = f2bf(f0.y); v[2] = f2bf(f0.z); v[3] = f2bf(f0.w);
        v[4] = f2bf(f1.x); v[5] = f2bf(f1.y); v[6] = f2bf(f1.z); v[7] = f2bf(f1.w);
        *(bf16x8*)(smem + r * 512 + ((s * 16) ^ ((r & 7) << 4))) = v;
    }
    __syncthreads();
    f32x4 acc[6];
#pragma unroll
    for (int j = 0; j < 6; ++j) acc[j] = (f32x4){0.f, 0.f, 0.f, 0.f};
    {
        const int nbq = wave * 96;
        const short* wq_base = wq + (nbq + fr) * 256 + fq * 8;
#pragma unroll
        for (int ks = 0; ks < 8; ++ks) {
            const int kbyte = ks * 64 + fq * 16;
            bf16x8 bX = *(const bf16x8*)(smem + fr * 512 + (kbyte ^ ((fr & 7) << 4)));
            bf16x8 aW0 = *(const bf16x8*)(wq_base + 0 * 4096 + ks * 32);
            bf16x8 aW1 = *(const bf16x8*)(wq_base + 1 * 4096 + ks * 32);
            bf16x8 aW2 = *(const bf16x8*)(wq_base + 2 * 4096 + ks * 32);
            acc[0] = __builtin_amdgcn_mfma_f32_16x16x32_bf16(aW0, bX, acc[0], 0, 0, 0);
            acc[1] = __builtin_amdgcn_mfma_f32_16x16x32_bf16(aW1, bX, acc[1], 0, 0, 0);
            acc[2] = __builtin_amdgcn_mfma_f32_16x16x32_bf16(aW2, bX, acc[2], 0, 0, 0);
            bf16x8 aW3 = *(const bf16x8*)(wq_base + 3 * 4096 + ks * 32);
            bf16x8 aW4 = *(const bf16x8*)(wq_base + 4 * 4096 + ks * 32);
            bf16x8 aW5 = *(const bf16x8*)(wq_base + 5 * 4096 + ks * 32);
            acc[3] = __builtin_amdgcn_mfma_f32_16x16x32_bf16(aW3, bX, acc[3], 0, 0, 0);
            acc[4] = __builtin_amdgcn_mfma_f32_16x16x32_bf16(aW4, bX, acc[4], 0, 0, 0);
            acc[5] = __builtin_amdgcn_mfma_f32_16x16x32_bf16(aW5, bX, acc[5], 0, 0, 0);
        }
    }
    __syncthreads();
    {
        const int nbq = wave * 96;
#pragma unroll
        for (int j = 0; j < 6; ++j) {
            const int n0 = nbq + j * 16 + fq * 4;
            float4 bias = *(const float4*)(qkv_b + n0);
            bf16x4 y;
            y[0] = f2bf(acc[j][0] + bias.x);
            y[1] = f2bf(acc[j][1] + bias.y);
            y[2] = f2bf(acc[j][2] + bias.z);
            y[3] = f2bf(acc[j][3] + bias.w);
            *(bf16x4*)(smem + fr * 1552 + n0 * 2) = y;
        }
    }
    __syncthreads();
    float o[8];
    int orow, ocol;
    {
        const int t = tid >> 5, sub = tid & 31;
        const int h = sub & 7, qt = sub >> 3;
        const char* Yrow = smem + t * 1552;
        const float scale = 0.17677669529663687f;
        float q[8];
        {
            bf16x8 qv = *(const bf16x8*)(Yrow + h * 64 + qt * 16);
#pragma unroll
            for (int c = 0; c < 8; ++c) q[c] = bf2f(qv[c]);
        }
        float s[8];
#pragma unroll
        for (int g = 0; g < 8; ++g) {
            bf16x8 kv = *(const bf16x8*)(Yrow + 512 + g * 64 + qt * 16);
            float p = 0.f;
#pragma unroll
            for (int c = 0; c < 8; ++c) p += q[c] * bf2f(kv[c]);
            p += __shfl_xor(p, 8);
            p += __shfl_xor(p, 16);
            s[g] = p * scale;
        }
        float mx = s[0];
#pragma unroll
        for (int g = 1; g < 8; ++g) mx = fmaxf(mx, s[g]);
        float pw[8], psum = 0.f;
#pragma unroll
        for (int g = 0; g < 8; ++g) { pw[g] = __expf(s[g] - mx); psum += pw[g]; }
        const float inv = 1.f / psum;
#pragma unroll
        for (int c = 0; c < 8; ++c) o[c] = 0.f;
#pragma unroll
        for (int g = 0; g < 8; ++g) {
            bf16x8 vv = *(const bf16x8*)(Yrow + 1024 + g * 64 + qt * 16);
#pragma unroll
            for (int c = 0; c < 8; ++c) o[c] += pw[g] * bf2f(vv[c]);
        }
#pragma unroll
        for (int c = 0; c < 8; ++c) o[c] *= inv;
        orow = h * 2 + (t >> 3);
        ocol = (t & 7) * 64 + qt * 16;
    }
    __syncthreads();
    {
        bf16x8 ov;
#pragma unroll
        for (int c = 0; c < 8; ++c) ov[c] = f2bf(o[c]);
        *(bf16x8*)(smem + orow * 512 + (ocol ^ ((orow & 7) << 4))) = ov;
    }
    __syncthreads();
    {
        const int nbp = wave * 32;
        const short* wp_base = wp + (nbp + fr) * 256 + fq * 8;
        f32x4 pacc0 = (f32x4){0.f, 0.f, 0.f, 0.f};
        f32x4 pacc1 = (f32x4){0.f, 0.f, 0.f, 0.f};
#pragma unroll
        for (int ks = 0; ks < 8; ++ks) {
            bf16x8 bO = *(const bf16x8*)(smem + fr * 512 + ((ks * 64 + fq * 16) ^ ((fr & 7) << 4)));
            bf16x8 w0 = *(const bf16x8*)(wp_base + ks * 32);
            bf16x8 w1 = *(const bf16x8*)(wp_base + 4096 + ks * 32);
            pacc0 = __builtin_amdgcn_mfma_f32_16x16x32_bf16(w0, bO, pacc0, 0, 0, 0);
            pacc1 = __builtin_amdgcn_mfma_f32_16x16x32_bf16(w1, bO, pacc1, 0, 0, 0);
        }
        const int h = fr >> 1, oct = fr & 1;
        const long b = (long)(t0 >> 11);
        const int n = t0 & 2047;
        const long rp = b * 2048 + h * 256 + (n >> 3) + oct;
        {
            const int n0 = nbp + fq * 4;
            float4 bias = *(const float4*)(proj_b + n0);
            float4 res = {pacc0[0] + bias.x, pacc0[1] + bias.y,
                          pacc0[2] + bias.z, pacc0[3] + bias.w};
            *(float4*)(out + rp * 256 + n0) = res;
        }
        {
            const int n0 = nbp + 16 + fq * 4;
            float4 bias = *(const float4*)(proj_b + n0);
            float4 res = {pacc1[0] + bias.x, pacc1[1] + bias.y,
                          pacc1[2] + bias.z, pacc1[3] + bias.w};
            *(float4*)(out + rp * 256 + n0) = res;
        }
    }
}

extern "C" void kernel_launch(void* const* d_in, const int* in_sizes, int n_in,
                              void* d_out, int out_size, void* d_ws, size_t ws_size,
                              hipStream_t stream) {
    const float* x      = (const float*)d_in[0];
    const float* qkv_w  = (const float*)d_in[1];
    const float* qkv_b  = (const float*)d_in[2];
    const float* proj_w = (const float*)d_in[3];
    const float* proj_b = (const float*)d_in[4];
    float* out = (float*)d_out;
    char* ws = (char*)d_ws;

    const size_t Y_BYTES    = 201326592ULL;  // 131072*768*2
    const size_t O2_BYTES   = 67108864ULL;   // 131072*256*2
    const size_t WQ_BYTES   = 393216ULL;
    const size_t WP_BYTES   = 131072ULL;
    const size_t NEED = Y_BYTES + O2_BYTES + WQ_BYTES + WP_BYTES;

    if (ws_size >= NEED) {
        short* Y     = (short*)ws;
        short* out2  = (short*)(ws + Y_BYTES);
        short* wq_bf = (short*)(ws + Y_BYTES + O2_BYTES);
        short* wp_bf = (short*)(ws + Y_BYTES + O2_BYTES + WQ_BYTES);
        k0_convert<<<1024, 256, 0, stream>>>(qkv_w, proj_w, wq_bf, wp_bf);
        k1_qkv<<<1536, 256, 0, stream>>>(x, wq_bf, qkv_b, Y);
        k2_attn<<<1024, 512, 0, stream>>>(Y, out2);
        k3_proj<<<2048, 256, 0, stream>>>(out2, wp_bf, proj_b, out);
    } else {
        short* wq_bf = (short*)ws;
        short* wp_bf = (short*)(ws + WQ_BYTES);
        k0_convert<<<1024, 256, 0, stream>>>(qkv_w, proj_w, wq_bf, wp_bf);
        k1_fused<<<8192, 512, 0, stream>>>(x, wq_bf, qkv_b, wp_bf, proj_b, out);
    }
}

// Round 10
// 445.212 us; speedup vs baseline: 1.4787x; 1.2728x over previous
//
#include <hip/hip_runtime.h>
#include <hip/hip_bf16.h>

// B=64, N=2048, C=256, H=8, Ch=32, M=131072, qkv dim=768
// r10: all-bf16 dataflow, m97-style GEMMs (global_load_lds, linear LDS, 2-barrier).
// k0: x+weights -> bf16 | k1: QKV GEMM -> Y | k2: attention -> out2 | k3: proj -> out

typedef __attribute__((ext_vector_type(8))) short bf16x8;
typedef __attribute__((ext_vector_type(4))) short bf16x4;
typedef __attribute__((ext_vector_type(4))) float f32x4;

__device__ __forceinline__ short f2bf(float f) {
    unsigned u = __builtin_bit_cast(unsigned, f);
    unsigned r = (u + 0x7FFFu + ((u >> 16) & 1u)) >> 16;  // RNE
    return (short)r;
}
__device__ __forceinline__ float bf2f(short h) {
    unsigned u = ((unsigned)(unsigned short)h) << 16;
    return __builtin_bit_cast(float, u);
}
__device__ __forceinline__ void gload16(const void* g, void* l) {
    __builtin_amdgcn_global_load_lds(
        (const __attribute__((address_space(1))) unsigned int*)g,
        (__attribute__((address_space(3))) unsigned int*)l, 16, 0, 0);
}

// ---------------- K0: convert x + weights fp32 -> bf16 (8 elems/thread) ----------------
__global__ void k0_convert_all(const float* __restrict__ x,
                               const float* __restrict__ qkv_w,
                               const float* __restrict__ proj_w,
                               short* __restrict__ xbf,
                               short* __restrict__ wq,
                               short* __restrict__ wp) {
    const long c = (long)blockIdx.x * 256 + threadIdx.x;   // 4,227,072 chunks total
    const float* src; short* dst; long off;
    if (c < 4194304) { src = x; dst = xbf; off = c; }
    else if (c < 4218880) { src = qkv_w; dst = wq; off = c - 4194304; }
    else { src = proj_w; dst = wp; off = c - 4218880; }
    const float4* p = (const float4*)(src + off * 8);
    float4 a = p[0], b = p[1];
    bf16x8 v;
    v[0] = f2bf(a.x); v[1] = f2bf(a.y); v[2] = f2bf(a.z); v[3] = f2bf(a.w);
    v[4] = f2bf(b.x); v[5] = f2bf(b.y); v[6] = f2bf(b.z); v[7] = f2bf(b.w);
    *(bf16x8*)(dst + off * 8) = v;
}

// ---------------- K0b: weights only (fallback path) ----------------
__global__ void k0_convert_w(const float* __restrict__ qkv_w,
                             const float* __restrict__ proj_w,
                             short* __restrict__ wq_bf,
                             short* __restrict__ wp_bf) {
    int i = blockIdx.x * 256 + threadIdx.x;   // 262144 total
    if (i < 196608) wq_bf[i] = f2bf(qkv_w[i]);
    else            wp_bf[i - 196608] = f2bf(proj_w[i - 196608]);
}

// ---------------- K1: QKV GEMM  Y[M][768] = xbf @ wq^T + b ----------------
// 256 thr (4 waves 2x2), tile 128x128, BK=32, 8 K-steps, grid 6144 (mt*6+nt).
// m97 structure: global_load_lds width=16 both operands, linear LDS [128][32],
// 2 barriers per K-step. Frag ds_read_b128 pattern is bank-conflict-free.
__global__ __launch_bounds__(256, 3) void k1_qkv(
    const short* __restrict__ xbf,    // [131072][256] bf16
    const short* __restrict__ wq,     // [768][256] bf16
    const float* __restrict__ qkv_b,  // [768] fp32
    short* __restrict__ Y)            // [131072][768] bf16
{
    __shared__ __align__(16) short As[4096];   // [128 rows][32 shorts] linear
    __shared__ __align__(16) short Bs[4096];
    const int tid = threadIdx.x, lane = tid & 63, wave = tid >> 6;
    const int wr = wave >> 1, wc = wave & 1;
    const int fr = lane & 15, fq = lane >> 4;
    const int mt = blockIdx.x / 6, nt = blockIdx.x % 6;
    const long m0 = (long)mt * 128;
    const int n0 = nt * 128;

    // staging: wave handles LDS runs {2w, 2w+1} for A and for B.
    // run r (1KB): rows [16r,16r+16); lane l -> row 16r+(l>>2), col shorts (l&3)*8
    const int rA = 2 * wave;
    const int lrow = lane >> 2, lcol = lane & 3;
    const short* gA0 = xbf + (m0 + rA * 16 + lrow) * 256 + lcol * 8;
    const short* gA1 = xbf + (m0 + rA * 16 + 16 + lrow) * 256 + lcol * 8;
    const short* gB0 = wq + (long)(n0 + rA * 16 + lrow) * 256 + lcol * 8;
    const short* gB1 = wq + (long)(n0 + rA * 16 + 16 + lrow) * 256 + lcol * 8;
    short* lA0 = &As[rA * 512 + lane * 8];
    short* lA1 = &As[(rA + 1) * 512 + lane * 8];
    short* lB0 = &Bs[rA * 512 + lane * 8];
    short* lB1 = &Bs[(rA + 1) * 512 + lane * 8];

    f32x4 acc[4][4];
#pragma unroll
    for (int i = 0; i < 4; ++i)
#pragma unroll
        for (int j = 0; j < 4; ++j) acc[i][j] = (f32x4){0.f, 0.f, 0.f, 0.f};

#pragma unroll
    for (int ks = 0; ks < 8; ++ks) {
        __syncthreads();                    // prev frag reads done before overwrite
        gload16(gA0 + ks * 32, lA0);
        gload16(gA1 + ks * 32, lA1);
        gload16(gB0 + ks * 32, lB0);
        gload16(gB1 + ks * 32, lB1);
        __syncthreads();                    // compiler drains vmcnt before barrier
        bf16x8 af[4], bff[4];
#pragma unroll
        for (int nj = 0; nj < 4; ++nj)
            af[nj] = *(const bf16x8*)(&Bs[(wc * 64 + nj * 16 + fr) * 32 + fq * 8]);
#pragma unroll
        for (int mi = 0; mi < 4; ++mi)
            bff[mi] = *(const bf16x8*)(&As[(wr * 64 + mi * 16 + fr) * 32 + fq * 8]);
#pragma unroll
        for (int mi = 0; mi < 4; ++mi)
#pragma unroll
            for (int nj = 0; nj < 4; ++nj)
                acc[mi][nj] = __builtin_amdgcn_mfma_f32_16x16x32_bf16(af[nj], bff[mi], acc[mi][nj], 0, 0, 0);
    }
    // epilogue: bias + bf16 store (mapping validated in r9)
#pragma unroll
    for (int mi = 0; mi < 4; ++mi) {
        const long m = m0 + wr * 64 + mi * 16 + fr;
#pragma unroll
        for (int nj = 0; nj < 4; ++nj) {
            const int nc = n0 + wc * 64 + nj * 16 + fq * 4;
            float4 bb = *(const float4*)(qkv_b + nc);
            bf16x4 y;
            y[0] = f2bf(acc[mi][nj][0] + bb.x);
            y[1] = f2bf(acc[mi][nj][1] + bb.y);
            y[2] = f2bf(acc[mi][nj][2] + bb.z);
            y[3] = f2bf(acc[mi][nj][3] + bb.w);
            *(bf16x4*)(&Y[m * 768 + nc]) = y;
        }
    }
}

// ---------------- K2: attention  Y -> out2 (shuffled layout, coalesced) ----------------
// 8192 blocks x 512 thr, 16 tokens/block, 32 thr/token; LDS-assemble 16 full
// out2 rows (512B each), then contiguous row writes.
__global__ __launch_bounds__(512) void k2_attn(
    const short* __restrict__ Y,      // [131072][768] bf16
    short* __restrict__ out2)         // [131072][256] bf16, shuffled
{
    __shared__ __align__(16) char sm[16 * 528];   // 16 rows, 512B + 16B pad
    const int tid = threadIdx.x;
    const int t = tid >> 5, sub = tid & 31;
    const int h = sub & 7, qt = sub >> 3;
    const long t0 = (long)blockIdx.x * 16;
    const float scale = 0.17677669529663687f;     // 1/sqrt(32)

    const short* Yr = Y + (t0 + t) * 768;
    float q[8];
    {
        bf16x8 qv = *(const bf16x8*)(Yr + h * 32 + qt * 8);
#pragma unroll
        for (int c = 0; c < 8; ++c) q[c] = bf2f(qv[c]);
    }
    float s[8];
#pragma unroll
    for (int g = 0; g < 8; ++g) {
        bf16x8 kv = *(const bf16x8*)(Yr + 256 + g * 32 + qt * 8);
        float pp = 0.f;
#pragma unroll
        for (int c = 0; c < 8; ++c) pp += q[c] * bf2f(kv[c]);
        pp += __shfl_xor(pp, 8);
        pp += __shfl_xor(pp, 16);
        s[g] = pp * scale;
    }
    float mx = s[0];
#pragma unroll
    for (int g = 1; g < 8; ++g) mx = fmaxf(mx, s[g]);
    float pw[8], psum = 0.f;
#pragma unroll
    for (int g = 0; g < 8; ++g) { pw[g] = __expf(s[g] - mx); psum += pw[g]; }
    const float inv = 1.f / psum;
    float o[8];
#pragma unroll
    for (int c = 0; c < 8; ++c) o[c] = 0.f;
#pragma unroll
    for (int g = 0; g < 8; ++g) {
        bf16x8 vv = *(const bf16x8*)(Yr + 512 + g * 32 + qt * 8);
#pragma unroll
        for (int c = 0; c < 8; ++c) o[c] += pw[g] * bf2f(vv[c]);
    }
    // assemble: LDS row R = (t>>3)*8 + h, col bytes (t&7)*64 + qt*16
    {
        bf16x8 ov;
#pragma unroll
        for (int c = 0; c < 8; ++c) ov[c] = f2bf(o[c] * inv);
        const int R = (t >> 3) * 8 + h;
        *(bf16x8*)(sm + R * 528 + (t & 7) * 64 + qt * 16) = ov;
    }
    __syncthreads();
    // write out: thread i -> row i>>5, 16B segment i&31
    {
        const int R2 = tid >> 5, seg = tid & 31;
        bf16x8 v = *(const bf16x8*)(sm + R2 * 528 + seg * 16);
        const long b = t0 >> 11;
        const int n0b = (int)(t0 & 2047);
        const long grow = b * 2048 + (long)(R2 & 7) * 256 + (n0b >> 3) + (R2 >> 3);
        *(bf16x8*)(out2 + grow * 256 + seg * 8) = v;
    }
}

// ---------------- K3: proj GEMM  out[M][256] = out2 @ wp^T + b ----------------
// Same m97 structure; grid 2048 (mt*2+nt), fp32 output.
__global__ __launch_bounds__(256, 3) void k3_proj(
    const short* __restrict__ out2,   // [131072][256] bf16
    const short* __restrict__ wp,     // [256][256] bf16
    const float* __restrict__ proj_b, // [256] fp32
    float* __restrict__ out)          // [131072][256] fp32
{
    __shared__ __align__(16) short As[4096];
    __shared__ __align__(16) short Bs[4096];
    const int tid = threadIdx.x, lane = tid & 63, wave = tid >> 6;
    const int wr = wave >> 1, wc = wave & 1;
    const int fr = lane & 15, fq = lane >> 4;
    const long m0 = (long)(blockIdx.x >> 1) * 128;
    const int n0 = (blockIdx.x & 1) * 128;

    const int rA = 2 * wave;
    const int lrow = lane >> 2, lcol = lane & 3;
    const short* gA0 = out2 + (m0 + rA * 16 + lrow) * 256 + lcol * 8;
    const short* gA1 = out2 + (m0 + rA * 16 + 16 + lrow) * 256 + lcol * 8;
    const short* gB0 = wp + (long)(n0 + rA * 16 + lrow) * 256 + lcol * 8;
    const short* gB1 = wp + (long)(n0 + rA * 16 + 16 + lrow) * 256 + lcol * 8;
    short* lA0 = &As[rA * 512 + lane * 8];
    short* lA1 = &As[(rA + 1) * 512 + lane * 8];
    short* lB0 = &Bs[rA * 512 + lane * 8];
    short* lB1 = &Bs[(rA + 1) * 512 + lane * 8];

    f32x4 acc[4][4];
#pragma unroll
    for (int i = 0; i < 4; ++i)
#pragma unroll
        for (int j = 0; j < 4; ++j) acc[i][j] = (f32x4){0.f, 0.f, 0.f, 0.f};

#pragma unroll
    for (int ks = 0; ks < 8; ++ks) {
        __syncthreads();
        gload16(gA0 + ks * 32, lA0);
        gload16(gA1 + ks * 32, lA1);
        gload16(gB0 + ks * 32, lB0);
        gload16(gB1 + ks * 32, lB1);
        __syncthreads();
        bf16x8 af[4], bff[4];
#pragma unroll
        for (int nj = 0; nj < 4; ++nj)
            af[nj] = *(const bf16x8*)(&Bs[(wc * 64 + nj * 16 + fr) * 32 + fq * 8]);
#pragma unroll
        for (int mi = 0; mi < 4; ++mi)
            bff[mi] = *(const bf16x8*)(&As[(wr * 64 + mi * 16 + fr) * 32 + fq * 8]);
#pragma unroll
        for (int mi = 0; mi < 4; ++mi)
#pragma unroll
            for (int nj = 0; nj < 4; ++nj)
                acc[mi][nj] = __builtin_amdgcn_mfma_f32_16x16x32_bf16(af[nj], bff[mi], acc[mi][nj], 0, 0, 0);
    }
#pragma unroll
    for (int mi = 0; mi < 4; ++mi) {
        const long m = m0 + wr * 64 + mi * 16 + fr;
#pragma unroll
        for (int nj = 0; nj < 4; ++nj) {
            const int nc = n0 + wc * 64 + nj * 16 + fq * 4;
            float4 bb = *(const float4*)(proj_b + nc);
            float4 res = {acc[mi][nj][0] + bb.x, acc[mi][nj][1] + bb.y,
                          acc[mi][nj][2] + bb.z, acc[mi][nj][3] + bb.w};
            *(float4*)(out + m * 256 + nc) = res;
        }
    }
}

// ================= r8 fused kernel: fallback if ws too small =================
__global__ __launch_bounds__(512, 6) void k1_fused(
    const float* __restrict__ x, const short* __restrict__ wq,
    const float* __restrict__ qkv_b, const short* __restrict__ wp,
    const float* __restrict__ proj_b, float* __restrict__ out)
{
    __shared__ __align__(16) char smem[24832];
    const int tid = threadIdx.x;
    const int lane = tid & 63;
    const int wave = tid >> 6;
    const int t0 = blockIdx.x * 16;
    const int fr = lane & 15, fq = lane >> 4;
    {
        const int r = tid >> 5, s = tid & 31;
        const float4* src = (const float4*)(x + (long)(t0 + r) * 256 + s * 8);
        float4 f0 = src[0], f1 = src[1];
        bf16x8 v;
        v[0] = f2bf(f0.x); v[1] = f2bf(f0.y); v[2] = f2bf(f0.z); v[3] = f2bf(f0.w);
        v[4] = f2bf(f1.x); v[5] = f2bf(f1.y); v[6] = f2bf(f1.z); v[7] = f2bf(f1.w);
        *(bf16x8*)(smem + r * 512 + ((s * 16) ^ ((r & 7) << 4))) = v;
    }
    __syncthreads();
    f32x4 acc[6];
#pragma unroll
    for (int j = 0; j < 6; ++j) acc[j] = (f32x4){0.f, 0.f, 0.f, 0.f};
    {
        const int nbq = wave * 96;
        const short* wq_base = wq + (nbq + fr) * 256 + fq * 8;
#pragma unroll
        for (int ks = 0; ks < 8; ++ks) {
            const int kbyte = ks * 64 + fq * 16;
            bf16x8 bX = *(const bf16x8*)(smem + fr * 512 + (kbyte ^ ((fr & 7) << 4)));
            bf16x8 aW0 = *(const bf16x8*)(wq_base + 0 * 4096 + ks * 32);
            bf16x8 aW1 = *(const bf16x8*)(wq_base + 1 * 4096 + ks * 32);
            bf16x8 aW2 = *(const bf16x8*)(wq_base + 2 * 4096 + ks * 32);
            acc[0] = __builtin_amdgcn_mfma_f32_16x16x32_bf16(aW0, bX, acc[0], 0, 0, 0);
            acc[1] = __builtin_amdgcn_mfma_f32_16x16x32_bf16(aW1, bX, acc[1], 0, 0, 0);
            acc[2] = __builtin_amdgcn_mfma_f32_16x16x32_bf16(aW2, bX, acc[2], 0, 0, 0);
            bf16x8 aW3 = *(const bf16x8*)(wq_base + 3 * 4096 + ks * 32);
            bf16x8 aW4 = *(const bf16x8*)(wq_base + 4 * 4096 + ks * 32);
            bf16x8 aW5 = *(const bf16x8*)(wq_base + 5 * 4096 + ks * 32);
            acc[3] = __builtin_amdgcn_mfma_f32_16x16x32_bf16(aW3, bX, acc[3], 0, 0, 0);
            acc[4] = __builtin_amdgcn_mfma_f32_16x16x32_bf16(aW4, bX, acc[4], 0, 0, 0);
            acc[5] = __builtin_amdgcn_mfma_f32_16x16x32_bf16(aW5, bX, acc[5], 0, 0, 0);
        }
    }
    __syncthreads();
    {
        const int nbq = wave * 96;
#pragma unroll
        for (int j = 0; j < 6; ++j) {
            const int n0 = nbq + j * 16 + fq * 4;
            float4 bias = *(const float4*)(qkv_b + n0);
            bf16x4 y;
            y[0] = f2bf(acc[j][0] + bias.x);
            y[1] = f2bf(acc[j][1] + bias.y);
            y[2] = f2bf(acc[j][2] + bias.z);
            y[3] = f2bf(acc[j][3] + bias.w);
            *(bf16x4*)(smem + fr * 1552 + n0 * 2) = y;
        }
    }
    __syncthreads();
    float o[8];
    int orow, ocol;
    {
        const int t = tid >> 5, sub = tid & 31;
        const int h = sub & 7, qt = sub >> 3;
        const char* Yrow = smem + t * 1552;
        const float scale = 0.17677669529663687f;
        float q[8];
        {
            bf16x8 qv = *(const bf16x8*)(Yrow + h * 64 + qt * 16);
#pragma unroll
            for (int c = 0; c < 8; ++c) q[c] = bf2f(qv[c]);
        }
        float s[8];
#pragma unroll
        for (int g = 0; g < 8; ++g) {
            bf16x8 kv = *(const bf16x8*)(Yrow + 512 + g * 64 + qt * 16);
            float p = 0.f;
#pragma unroll
            for (int c = 0; c < 8; ++c) p += q[c] * bf2f(kv[c]);
            p += __shfl_xor(p, 8);
            p += __shfl_xor(p, 16);
            s[g] = p * scale;
        }
        float mx = s[0];
#pragma unroll
        for (int g = 1; g < 8; ++g) mx = fmaxf(mx, s[g]);
        float pw[8], psum = 0.f;
#pragma unroll
        for (int g = 0; g < 8; ++g) { pw[g] = __expf(s[g] - mx); psum += pw[g]; }
        const float inv = 1.f / psum;
#pragma unroll
        for (int c = 0; c < 8; ++c) o[c] = 0.f;
#pragma unroll
        for (int g = 0; g < 8; ++g) {
            bf16x8 vv = *(const bf16x8*)(Yrow + 1024 + g * 64 + qt * 16);
#pragma unroll
            for (int c = 0; c < 8; ++c) o[c] += pw[g] * bf2f(vv[c]);
        }
#pragma unroll
        for (int c = 0; c < 8; ++c) o[c] *= inv;
        orow = h * 2 + (t >> 3);
        ocol = (t & 7) * 64 + qt * 16;
    }
    __syncthreads();
    {
        bf16x8 ov;
#pragma unroll
        for (int c = 0; c < 8; ++c) ov[c] = f2bf(o[c]);
        *(bf16x8*)(smem + orow * 512 + (ocol ^ ((orow & 7) << 4))) = ov;
    }
    __syncthreads();
    {
        const int nbp = wave * 32;
        const short* wp_base = wp + (nbp + fr) * 256 + fq * 8;
        f32x4 pacc0 = (f32x4){0.f, 0.f, 0.f, 0.f};
        f32x4 pacc1 = (f32x4){0.f, 0.f, 0.f, 0.f};
#pragma unroll
        for (int ks = 0; ks < 8; ++ks) {
            bf16x8 bO = *(const bf16x8*)(smem + fr * 512 + ((ks * 64 + fq * 16) ^ ((fr & 7) << 4)));
            bf16x8 w0 = *(const bf16x8*)(wp_base + ks * 32);
            bf16x8 w1 = *(const bf16x8*)(wp_base + 4096 + ks * 32);
            pacc0 = __builtin_amdgcn_mfma_f32_16x16x32_bf16(w0, bO, pacc0, 0, 0, 0);
            pacc1 = __builtin_amdgcn_mfma_f32_16x16x32_bf16(w1, bO, pacc1, 0, 0, 0);
        }
        const int h = fr >> 1, oct = fr & 1;
        const long b = (long)(t0 >> 11);
        const int n = t0 & 2047;
        const long rp = b * 2048 + h * 256 + (n >> 3) + oct;
        {
            const int n0 = nbp + fq * 4;
            float4 bias = *(const float4*)(proj_b + n0);
            float4 res = {pacc0[0] + bias.x, pacc0[1] + bias.y,
                          pacc0[2] + bias.z, pacc0[3] + bias.w};
            *(float4*)(out + rp * 256 + n0) = res;
        }
        {
            const int n0 = nbp + 16 + fq * 4;
            float4 bias = *(const float4*)(proj_b + n0);
            float4 res = {pacc1[0] + bias.x, pacc1[1] + bias.y,
                          pacc1[2] + bias.z, pacc1[3] + bias.w};
            *(float4*)(out + rp * 256 + n0) = res;
        }
    }
}

extern "C" void kernel_launch(void* const* d_in, const int* in_sizes, int n_in,
                              void* d_out, int out_size, void* d_ws, size_t ws_size,
                              hipStream_t stream) {
    const float* x      = (const float*)d_in[0];
    const float* qkv_w  = (const float*)d_in[1];
    const float* qkv_b  = (const float*)d_in[2];
    const float* proj_w = (const float*)d_in[3];
    const float* proj_b = (const float*)d_in[4];
    float* out = (float*)d_out;
    char* ws = (char*)d_ws;

    const size_t XBF_BYTES = 67108864ULL;    // 131072*256*2
    const size_t Y_BYTES   = 201326592ULL;   // 131072*768*2
    const size_t O2_BYTES  = 67108864ULL;    // 131072*256*2
    const size_t WQ_BYTES  = 393216ULL;
    const size_t WP_BYTES  = 131072ULL;
    const size_t NEED = XBF_BYTES + Y_BYTES + O2_BYTES + WQ_BYTES + WP_BYTES;

    if (ws_size >= NEED) {
        short* xbf   = (short*)ws;
        short* Y     = (short*)(ws + XBF_BYTES);
        short* out2  = (short*)(ws + XBF_BYTES + Y_BYTES);
        short* wq_bf = (short*)(ws + XBF_BYTES + Y_BYTES + O2_BYTES);
        short* wp_bf = (short*)(ws + XBF_BYTES + Y_BYTES + O2_BYTES + WQ_BYTES);
        k0_convert_all<<<16512, 256, 0, stream>>>(x, qkv_w, proj_w, xbf, wq_bf, wp_bf);
        k1_qkv<<<6144, 256, 0, stream>>>(xbf, wq_bf, qkv_b, Y);
        k2_attn<<<8192, 512, 0, stream>>>(Y, out2);
        k3_proj<<<2048, 256, 0, stream>>>(out2, wp_bf, proj_b, out);
    } else {
        short* wq_bf = (short*)ws;
        short* wp_bf = (short*)(ws + WQ_BYTES);
        k0_convert_w<<<1024, 256, 0, stream>>>(qkv_w, proj_w, wq_bf, wp_bf);
        k1_fused<<<8192, 512, 0, stream>>>(x, wq_bf, qkv_b, wp_bf, proj_b, out);
    }
}